// Round 27
// baseline (1678.084 us; speedup 1.0000x reference)
//
#include <hip/hip_runtime.h>

// AffinityPropagate (CSPN): B=8, C=32, H=W=256, K=3, prop_time=16.
// R25: R21 (CHUNK=32 wave-autonomous 4-step register pipeline) + 2 CHANNELS
// PER WAVE (c, c+16). The 4 live weight rows (144 VGPR) are channel-
// invariant: amortizing them over 2 channels halves weight-load traffic and
// doubles independent fmaf chains between dependent loads (ILP, not TLP —
// R22 proved resident waves are capped ~6.4/CU regardless of grid).
// Channel arrays fully unrolled -> compile-time indices (no scratch).

#define B_ 8
#define C_ 32
#define H_ 256
#define W_ 256
#define CHUNK 32
#define NF 40   // fronts f0..f0+39; needed = CHUNK+6 = 38, rounded to 4

// Planar weights: wts[((b*9)+j)*H*W + h*W + w]
__global__ __launch_bounds__(256)
void prep_weights_kernel(const float* __restrict__ guided,
                         const float* __restrict__ depth,
                         float* __restrict__ wts,
                         int total /* B*H*W */) {
    int idx = blockIdx.x * 256 + threadIdx.x;
    if (idx >= total) return;
    int b  = idx >> 16;        // H*W = 65536
    int hw = idx & 0xFFFF;
    const float* gp = guided + (((size_t)b * 8) << 16) + hw;
    float g[8];
    float m = -3.4e38f;
#pragma unroll
    for (int j = 0; j < 8; j++) { g[j] = gp[(size_t)j << 16]; m = fmaxf(m, g[j]); }
    float s = 0.f;
#pragma unroll
    for (int j = 0; j < 8; j++) { g[j] = expf(g[j] - m); s += g[j]; }
    float inv = 1.0f / s;
    float d = depth[(((size_t)b) << 16) + hw];
    bool fixed = d > 0.f;   // sign(depth) is 0/1 (depth >= 0)
    float* wp = wts + (((size_t)b * 9) << 16) + hw;
#pragma unroll
    for (int j = 0; j < 9; j++) {
        float v;
        if (j == 4) v = fixed ? 1.f : 0.f;            // center
        else        v = fixed ? 0.f : g[j - (j > 4 ? 1 : 0)] * inv;
        wp[(size_t)j << 16] = v;
    }
}

__device__ __forceinline__ float4 zero4() { return make_float4(0.f, 0.f, 0.f, 0.f); }

__device__ __forceinline__ float4 ldxrow(const float* xc, int row, int w0) {
    if (row < 0 || row >= H_) return zero4();
    return *reinterpret_cast<const float4*>(xc + (size_t)row * W_ + w0);
}

// acc[k] += wgt[3i+j][k] * rb[i][k+j]  — same fmaf order as R3..R22 (passed).
__device__ __forceinline__ void stencil4(const float wgt[9][4],
                                         const float rb[3][6],
                                         float acc[4]) {
#pragma unroll
    for (int i = 0; i < 3; ++i)
#pragma unroll
        for (int j = 0; j < 3; ++j)
#pragma unroll
            for (int k = 0; k < 4; ++k)
                acc[k] = fmaf(wgt[i * 3 + j][k], rb[i][k + j], acc[k]);
}

__device__ __forceinline__ void mkrb(float4 v, bool hasL, bool hasR, float rbrow[6]) {
    float lh = __shfl_up(v.w, 1);
    float rh = __shfl_down(v.x, 1);
    rbrow[0] = hasL ? lh : 0.f;
    rbrow[1] = v.x; rbrow[2] = v.y; rbrow[3] = v.z; rbrow[4] = v.w;
    rbrow[5] = hasR ? rh : 0.f;
}

__device__ __forceinline__ void load_wrow(const float* wb, int row, int w0,
                                          size_t plane, float (&w)[9][4]) {
    int qc = min(max(row, 0), H_ - 1);   // clamp; guarded consumers ignore
    const float* wp = wb + (size_t)qc * W_ + w0;
#pragma unroll
    for (int j = 0; j < 9; ++j) {
        float4 v = *reinterpret_cast<const float4*>(wp + j * plane);
        w[j][0] = v.x; w[j][1] = v.y; w[j][2] = v.z; w[j][3] = v.w;
    }
}

// One wave per block; 2 channels per wave (c0, c0+16).
__global__ __launch_bounds__(64, 2)
void prop_wave_kernel(const float* __restrict__ xin,
                      const float* __restrict__ wts,
                      float* __restrict__ xout) {
    const int tx = threadIdx.x;            // 0..63
    const int h0 = blockIdx.x * CHUNK;
    const int c0 = blockIdx.y;             // 0..15 -> channels c0, c0+16
    const int b  = blockIdx.z;
    const int w0 = tx * 4;
    const size_t plane = (size_t)H_ * W_;
    const bool hasL = (tx > 0), hasR = (tx < 63);
    const int f0 = h0 - 3;

    const float* xc[2] = {
        xin + ((size_t)b * C_ + c0) * plane,
        xin + ((size_t)b * C_ + c0 + 16) * plane };
    float* oc[2] = {
        xout + ((size_t)b * C_ + c0) * plane,
        xout + ((size_t)b * C_ + c0 + 16) * plane };
    const float* wb = wts + (size_t)b * 9 * plane;

    // per-channel x window and per-stage carried windows
    float4 xm[2], xq[2], xp[2];
    float4 s1a[2], s1b[2], s2a[2], s2b[2], s3a[2], s3b[2];
#pragma unroll
    for (int ch = 0; ch < 2; ++ch) {
        xm[ch] = ldxrow(xc[ch], f0 - 1, w0);
        xq[ch] = ldxrow(xc[ch], f0,     w0);
        xp[ch] = ldxrow(xc[ch], f0 + 1, w0);
        s1a[ch] = zero4(); s1b[ch] = zero4();
        s2a[ch] = zero4(); s2b[ch] = zero4();
        s3a[ch] = zero4(); s3b[ch] = zero4();
    }
    // 4 rotating weight-row buffers (channel-invariant): rows f, f-1, f-2, f-3
    float wg0[9][4], wg1[9][4], wg2[9][4], wg3[9][4];
    load_wrow(wb, f0,     w0, plane, wg0);
    load_wrow(wb, f0 - 1, w0, plane, wg1);
    load_wrow(wb, f0 - 2, w0, plane, wg2);
    load_wrow(wb, f0 - 3, w0, plane, wg3);

    auto front = [&](int f, const float (&w1)[9][4], const float (&w2)[9][4],
                     const float (&w3)[9][4], float (&w4)[9][4]) {
        float4 n1[2], n2[2], n3[2];
        // s1[f] (both channels — independent chains)
#pragma unroll
        for (int ch = 0; ch < 2; ++ch) {
            n1[ch] = zero4();
            if (f >= 0 && f < H_) {
                float rb[3][6];
                mkrb(xm[ch], hasL, hasR, rb[0]);
                mkrb(xq[ch], hasL, hasR, rb[1]);
                mkrb(xp[ch], hasL, hasR, rb[2]);
                float acc[4] = {0.f, 0.f, 0.f, 0.f};
                stencil4(w1, rb, acc);
                n1[ch] = make_float4(acc[0], acc[1], acc[2], acc[3]);
            }
        }
        // s2[f-1]
#pragma unroll
        for (int ch = 0; ch < 2; ++ch) {
            n2[ch] = zero4();
            if (f - 1 >= 0 && f - 1 < H_) {
                float rb[3][6];
                mkrb(s1a[ch], hasL, hasR, rb[0]);
                mkrb(s1b[ch], hasL, hasR, rb[1]);
                mkrb(n1[ch],  hasL, hasR, rb[2]);
                float acc[4] = {0.f, 0.f, 0.f, 0.f};
                stencil4(w2, rb, acc);
                n2[ch] = make_float4(acc[0], acc[1], acc[2], acc[3]);
            }
        }
        // s3[f-2]
#pragma unroll
        for (int ch = 0; ch < 2; ++ch) {
            n3[ch] = zero4();
            if (f - 2 >= 0 && f - 2 < H_) {
                float rb[3][6];
                mkrb(s2a[ch], hasL, hasR, rb[0]);
                mkrb(s2b[ch], hasL, hasR, rb[1]);
                mkrb(n2[ch],  hasL, hasR, rb[2]);
                float acc[4] = {0.f, 0.f, 0.f, 0.f};
                stencil4(w3, rb, acc);
                n3[ch] = make_float4(acc[0], acc[1], acc[2], acc[3]);
            }
        }
        // s4[f-3] -> store
        const int q = f - 3;
        if (q >= h0 && q < h0 + CHUNK) {
#pragma unroll
            for (int ch = 0; ch < 2; ++ch) {
                float rb[3][6];
                mkrb(s3a[ch], hasL, hasR, rb[0]);
                mkrb(s3b[ch], hasL, hasR, rb[1]);
                mkrb(n3[ch],  hasL, hasR, rb[2]);
                float acc[4] = {0.f, 0.f, 0.f, 0.f};
                stencil4(w4, rb, acc);
                *reinterpret_cast<float4*>(oc[ch] + (size_t)q * W_ + w0) =
                    make_float4(acc[0], acc[1], acc[2], acc[3]);
            }
        }
        // reload w4 with row f+1 (next front's s1 weights); prefetch x[f+2]
        load_wrow(wb, f + 1, w0, plane, w4);
#pragma unroll
        for (int ch = 0; ch < 2; ++ch) {
            float4 xn = ldxrow(xc[ch], f + 2, w0);
            xm[ch] = xq[ch]; xq[ch] = xp[ch]; xp[ch] = xn;
            s1a[ch] = s1b[ch]; s1b[ch] = n1[ch];
            s2a[ch] = s2b[ch]; s2b[ch] = n2[ch];
            s3a[ch] = s3b[ch]; s3b[ch] = n3[ch];
        }
    };

    // 4-unroll rotates weight buffers by NAME (no runtime indexing).
    for (int u = 0; u < NF; u += 4) {
        front(f0 + u + 0, wg0, wg1, wg2, wg3);   // loads f0+u+1 -> wg3
        front(f0 + u + 1, wg3, wg0, wg1, wg2);   // loads f0+u+2 -> wg2
        front(f0 + u + 2, wg2, wg3, wg0, wg1);   // loads f0+u+3 -> wg1
        front(f0 + u + 3, wg1, wg2, wg3, wg0);   // loads f0+u+4 -> wg0
    }
}

extern "C" void kernel_launch(void* const* d_in, const int* in_sizes, int n_in,
                              void* d_out, int out_size, void* d_ws, size_t ws_size,
                              hipStream_t stream) {
    const float* x      = (const float*)d_in[0];
    const float* guided = (const float*)d_in[1];
    const float* depth  = (const float*)d_in[2];
    // d_in[3] = prop_time; fixed to 16 by setup_inputs.
    const int DISPATCHES = 4;    // 16 steps, 4 per dispatch

    float* xbuf = (float*)d_ws;                                   // 64 MB
    float* wts  = (float*)((char*)d_ws +
                           (size_t)B_ * C_ * H_ * W_ * sizeof(float)); // 18.9 MB
    float* out  = (float*)d_out;

    int total = B_ * H_ * W_;
    hipLaunchKernelGGL(prep_weights_kernel, dim3((total + 255) / 256), dim3(256),
                       0, stream, guided, depth, wts, total);

    dim3 grid(H_ / CHUNK, C_ / 2, B_), block(64, 1, 1);   // 1024 x 1-wave blocks
    const float* src = x;
    for (int t = 0; t < DISPATCHES; ++t) {
        float* dst = (t == DISPATCHES - 1) ? out : ((t % 2 == 0) ? xbuf : out);
        hipLaunchKernelGGL(prop_wave_kernel, grid, block, 0, stream,
                           src, wts, dst);
        src = dst;
    }
}

// Round 28
// 370.681 us; speedup vs baseline: 4.5270x; 4.5270x over previous
//
#include <hip/hip_runtime.h>

// AffinityPropagate (CSPN): B=8, C=32, H=W=256, K=3, prop_time=16.
// R27: R25 (2 channels/wave ILP) with the register cap FIXED. R25's
// __launch_bounds__(64,2) let the allocator pin 128 VGPR (4-wave step) and
// spill ~40 regs -> 456 MB scratch writes. Dropping the min-waves bound
// lets allocation step to the 256-VGPR tier (2 waves/SIMD = 8/CU; measured
// residency was only ~6.4/CU anyway, so no TLP loss). Keeps: channel-
// invariant weight rows amortized over 2 channels, doubled fmaf ILP.

#define B_ 8
#define C_ 32
#define H_ 256
#define W_ 256
#define CHUNK 32
#define NF 40   // fronts f0..f0+39; needed = CHUNK+6 = 38, rounded to 4

// Planar weights: wts[((b*9)+j)*H*W + h*W + w]
__global__ __launch_bounds__(256)
void prep_weights_kernel(const float* __restrict__ guided,
                         const float* __restrict__ depth,
                         float* __restrict__ wts,
                         int total /* B*H*W */) {
    int idx = blockIdx.x * 256 + threadIdx.x;
    if (idx >= total) return;
    int b  = idx >> 16;        // H*W = 65536
    int hw = idx & 0xFFFF;
    const float* gp = guided + (((size_t)b * 8) << 16) + hw;
    float g[8];
    float m = -3.4e38f;
#pragma unroll
    for (int j = 0; j < 8; j++) { g[j] = gp[(size_t)j << 16]; m = fmaxf(m, g[j]); }
    float s = 0.f;
#pragma unroll
    for (int j = 0; j < 8; j++) { g[j] = expf(g[j] - m); s += g[j]; }
    float inv = 1.0f / s;
    float d = depth[(((size_t)b) << 16) + hw];
    bool fixed = d > 0.f;   // sign(depth) is 0/1 (depth >= 0)
    float* wp = wts + (((size_t)b * 9) << 16) + hw;
#pragma unroll
    for (int j = 0; j < 9; j++) {
        float v;
        if (j == 4) v = fixed ? 1.f : 0.f;            // center
        else        v = fixed ? 0.f : g[j - (j > 4 ? 1 : 0)] * inv;
        wp[(size_t)j << 16] = v;
    }
}

__device__ __forceinline__ float4 zero4() { return make_float4(0.f, 0.f, 0.f, 0.f); }

__device__ __forceinline__ float4 ldxrow(const float* xc, int row, int w0) {
    if (row < 0 || row >= H_) return zero4();
    return *reinterpret_cast<const float4*>(xc + (size_t)row * W_ + w0);
}

// acc[k] += wgt[3i+j][k] * rb[i][k+j]  — same fmaf order as R3..R25 (passed).
__device__ __forceinline__ void stencil4(const float wgt[9][4],
                                         const float rb[3][6],
                                         float acc[4]) {
#pragma unroll
    for (int i = 0; i < 3; ++i)
#pragma unroll
        for (int j = 0; j < 3; ++j)
#pragma unroll
            for (int k = 0; k < 4; ++k)
                acc[k] = fmaf(wgt[i * 3 + j][k], rb[i][k + j], acc[k]);
}

__device__ __forceinline__ void mkrb(float4 v, bool hasL, bool hasR, float rbrow[6]) {
    float lh = __shfl_up(v.w, 1);
    float rh = __shfl_down(v.x, 1);
    rbrow[0] = hasL ? lh : 0.f;
    rbrow[1] = v.x; rbrow[2] = v.y; rbrow[3] = v.z; rbrow[4] = v.w;
    rbrow[5] = hasR ? rh : 0.f;
}

__device__ __forceinline__ void load_wrow(const float* wb, int row, int w0,
                                          size_t plane, float (&w)[9][4]) {
    int qc = min(max(row, 0), H_ - 1);   // clamp; guarded consumers ignore
    const float* wp = wb + (size_t)qc * W_ + w0;
#pragma unroll
    for (int j = 0; j < 9; ++j) {
        float4 v = *reinterpret_cast<const float4*>(wp + j * plane);
        w[j][0] = v.x; w[j][1] = v.y; w[j][2] = v.z; w[j][3] = v.w;
    }
}

// One wave per block; 2 channels per wave (c0, c0+16). No min-waves bound:
// allocator free to use the 256-VGPR tier (R25 pinned 128 and spilled).
__global__ __launch_bounds__(64)
void prop_wave_kernel(const float* __restrict__ xin,
                      const float* __restrict__ wts,
                      float* __restrict__ xout) {
    const int tx = threadIdx.x;            // 0..63
    const int h0 = blockIdx.x * CHUNK;
    const int c0 = blockIdx.y;             // 0..15 -> channels c0, c0+16
    const int b  = blockIdx.z;
    const int w0 = tx * 4;
    const size_t plane = (size_t)H_ * W_;
    const bool hasL = (tx > 0), hasR = (tx < 63);
    const int f0 = h0 - 3;

    const float* xc[2] = {
        xin + ((size_t)b * C_ + c0) * plane,
        xin + ((size_t)b * C_ + c0 + 16) * plane };
    float* oc[2] = {
        xout + ((size_t)b * C_ + c0) * plane,
        xout + ((size_t)b * C_ + c0 + 16) * plane };
    const float* wb = wts + (size_t)b * 9 * plane;

    // per-channel x window and per-stage carried windows
    float4 xm[2], xq[2], xp[2];
    float4 s1a[2], s1b[2], s2a[2], s2b[2], s3a[2], s3b[2];
#pragma unroll
    for (int ch = 0; ch < 2; ++ch) {
        xm[ch] = ldxrow(xc[ch], f0 - 1, w0);
        xq[ch] = ldxrow(xc[ch], f0,     w0);
        xp[ch] = ldxrow(xc[ch], f0 + 1, w0);
        s1a[ch] = zero4(); s1b[ch] = zero4();
        s2a[ch] = zero4(); s2b[ch] = zero4();
        s3a[ch] = zero4(); s3b[ch] = zero4();
    }
    // 4 rotating weight-row buffers (channel-invariant): rows f, f-1, f-2, f-3
    float wg0[9][4], wg1[9][4], wg2[9][4], wg3[9][4];
    load_wrow(wb, f0,     w0, plane, wg0);
    load_wrow(wb, f0 - 1, w0, plane, wg1);
    load_wrow(wb, f0 - 2, w0, plane, wg2);
    load_wrow(wb, f0 - 3, w0, plane, wg3);

    auto front = [&](int f, const float (&w1)[9][4], const float (&w2)[9][4],
                     const float (&w3)[9][4], float (&w4)[9][4]) {
        float4 n1[2], n2[2], n3[2];
        // s1[f] (both channels — independent chains)
#pragma unroll
        for (int ch = 0; ch < 2; ++ch) {
            n1[ch] = zero4();
            if (f >= 0 && f < H_) {
                float rb[3][6];
                mkrb(xm[ch], hasL, hasR, rb[0]);
                mkrb(xq[ch], hasL, hasR, rb[1]);
                mkrb(xp[ch], hasL, hasR, rb[2]);
                float acc[4] = {0.f, 0.f, 0.f, 0.f};
                stencil4(w1, rb, acc);
                n1[ch] = make_float4(acc[0], acc[1], acc[2], acc[3]);
            }
        }
        // s2[f-1]
#pragma unroll
        for (int ch = 0; ch < 2; ++ch) {
            n2[ch] = zero4();
            if (f - 1 >= 0 && f - 1 < H_) {
                float rb[3][6];
                mkrb(s1a[ch], hasL, hasR, rb[0]);
                mkrb(s1b[ch], hasL, hasR, rb[1]);
                mkrb(n1[ch],  hasL, hasR, rb[2]);
                float acc[4] = {0.f, 0.f, 0.f, 0.f};
                stencil4(w2, rb, acc);
                n2[ch] = make_float4(acc[0], acc[1], acc[2], acc[3]);
            }
        }
        // s3[f-2]
#pragma unroll
        for (int ch = 0; ch < 2; ++ch) {
            n3[ch] = zero4();
            if (f - 2 >= 0 && f - 2 < H_) {
                float rb[3][6];
                mkrb(s2a[ch], hasL, hasR, rb[0]);
                mkrb(s2b[ch], hasL, hasR, rb[1]);
                mkrb(n2[ch],  hasL, hasR, rb[2]);
                float acc[4] = {0.f, 0.f, 0.f, 0.f};
                stencil4(w3, rb, acc);
                n3[ch] = make_float4(acc[0], acc[1], acc[2], acc[3]);
            }
        }
        // s4[f-3] -> store
        const int q = f - 3;
        if (q >= h0 && q < h0 + CHUNK) {
#pragma unroll
            for (int ch = 0; ch < 2; ++ch) {
                float rb[3][6];
                mkrb(s3a[ch], hasL, hasR, rb[0]);
                mkrb(s3b[ch], hasL, hasR, rb[1]);
                mkrb(n3[ch],  hasL, hasR, rb[2]);
                float acc[4] = {0.f, 0.f, 0.f, 0.f};
                stencil4(w4, rb, acc);
                *reinterpret_cast<float4*>(oc[ch] + (size_t)q * W_ + w0) =
                    make_float4(acc[0], acc[1], acc[2], acc[3]);
            }
        }
        // reload w4 with row f+1 (next front's s1 weights); prefetch x[f+2]
        load_wrow(wb, f + 1, w0, plane, w4);
#pragma unroll
        for (int ch = 0; ch < 2; ++ch) {
            float4 xn = ldxrow(xc[ch], f + 2, w0);
            xm[ch] = xq[ch]; xq[ch] = xp[ch]; xp[ch] = xn;
            s1a[ch] = s1b[ch]; s1b[ch] = n1[ch];
            s2a[ch] = s2b[ch]; s2b[ch] = n2[ch];
            s3a[ch] = s3b[ch]; s3b[ch] = n3[ch];
        }
    };

    // 4-unroll rotates weight buffers by NAME (no runtime indexing).
    for (int u = 0; u < NF; u += 4) {
        front(f0 + u + 0, wg0, wg1, wg2, wg3);   // loads f0+u+1 -> wg3
        front(f0 + u + 1, wg3, wg0, wg1, wg2);   // loads f0+u+2 -> wg2
        front(f0 + u + 2, wg2, wg3, wg0, wg1);   // loads f0+u+3 -> wg1
        front(f0 + u + 3, wg1, wg2, wg3, wg0);   // loads f0+u+4 -> wg0
    }
}

extern "C" void kernel_launch(void* const* d_in, const int* in_sizes, int n_in,
                              void* d_out, int out_size, void* d_ws, size_t ws_size,
                              hipStream_t stream) {
    const float* x      = (const float*)d_in[0];
    const float* guided = (const float*)d_in[1];
    const float* depth  = (const float*)d_in[2];
    // d_in[3] = prop_time; fixed to 16 by setup_inputs.
    const int DISPATCHES = 4;    // 16 steps, 4 per dispatch

    float* xbuf = (float*)d_ws;                                   // 64 MB
    float* wts  = (float*)((char*)d_ws +
                           (size_t)B_ * C_ * H_ * W_ * sizeof(float)); // 18.9 MB
    float* out  = (float*)d_out;

    int total = B_ * H_ * W_;
    hipLaunchKernelGGL(prep_weights_kernel, dim3((total + 255) / 256), dim3(256),
                       0, stream, guided, depth, wts, total);

    dim3 grid(H_ / CHUNK, C_ / 2, B_), block(64, 1, 1);   // 1024 x 1-wave blocks
    const float* src = x;
    for (int t = 0; t < DISPATCHES; ++t) {
        float* dst = (t == DISPATCHES - 1) ? out : ((t % 2 == 0) ? xbuf : out);
        hipLaunchKernelGGL(prop_wave_kernel, grid, block, 0, stream,
                           src, wts, dst);
        src = dst;
    }
}